// Round 10
// baseline (129.785 us; speedup 1.0000x reference)
//
#include <hip/hip_runtime.h>

#define N 4096

// XOR swizzle on float2 slot index; bijective, <=2-way bank aliasing for all
// patterns used (established R4-R8): T1w t*16+i | T1r/T2w b1*256+j*16+c1 | T2r j*256+t
__device__ __forceinline__ int swz(int e) { return e ^ ((e >> 4) & 15); }

template<bool BAR_BEFORE_WRITE, bool TOUCH>
__device__ __forceinline__ void do_pair(
    float2* lds, int t, int b1, int c1,
    float (&vA)[16], float (&vB)[16],                  // destroyed (scaled in place)
    const float* __restrict__ xA, const float* __restrict__ xB,
    float* __restrict__ oA, float* __restrict__ oB,
    const float* __restrict__ w0, const float* __restrict__ w1, const float* __restrict__ w2,
    const float* __restrict__ l0, const float* __restrict__ l1, const float* __restrict__ l2,
    const float (&tC)[16], const float (&tD)[16])      // next pair's regs to pin
{
    // ---- level 2 (thread-local 16x16 matvec, residual = x) -> registers ----
    float2 r2[16];
    #pragma unroll
    for (int i = 0; i < 16; ++i) r2[i] = make_float2(vA[i], vB[i]);   // residual init
    #pragma unroll
    for (int j = 0; j < 16; ++j) { float s = w2[j]; vA[j] *= s; vB[j] *= s; }
    #pragma unroll
    for (int i = 0; i < 16; ++i) {
        float a = r2[i].x, b = r2[i].y;
        #pragma unroll
        for (int j = 0; j < 16; ++j) {
            float s = l2[i*16 + j];                    // uniform -> SGPR
            a = fmaf(s, vA[j], a);
            b = fmaf(s, vB[j], b);
        }
        r2[i] = make_float2(a, b);
    }

    if (BAR_BEFORE_WRITE) __syncthreads();             // prev pair's LDS reads done
    #pragma unroll
    for (int i = 0; i < 16; ++i) lds[swz(t*16 + i)] = r2[i];   // wave-private region

    // ---- level 1 (intra-wave exchange, no barrier, no residual) ----
    float w1c[16];
    #pragma unroll
    for (int j = 0; j < 16; ++j) w1c[j] = w1[j*16 + c1];
    float2 y1[16];
    #pragma unroll
    for (int j = 0; j < 16; ++j) {
        float2 p = lds[swz(b1*256 + j*16 + c1)];       // same-wave writers
        y1[j].x = w1c[j] * p.x;
        y1[j].y = w1c[j] * p.y;
    }
    float2 r1[16];
    #pragma unroll
    for (int i = 0; i < 16; ++i) {
        float a = 0.f, b = 0.f;
        #pragma unroll
        for (int j = 0; j < 16; ++j) {
            float s = l1[i*16 + j];
            a = fmaf(s, y1[j].x, a);
            b = fmaf(s, y1[j].y, b);
        }
        r1[i] = make_float2(a, b);
    }
    #pragma unroll
    for (int i = 0; i < 16; ++i) lds[swz(b1*256 + i*16 + c1)] = r1[i];  // WAR, own wave

    if constexpr (TOUCH) {
        // pin next pair's loads: must be complete here (whole L2+L1 compute to hide),
        // prevents the compiler sinking them below this barrier (R2/R3 lesson)
        #pragma unroll
        for (int k = 0; k < 16; ++k)
            asm volatile("" :: "v"(tC[k]), "v"(tD[k]));
    }
    __syncthreads();                                   // the cross-wave handoff

    // ---- level 0 (stride-256 mix, residual = original x), NT full-line stores ----
    float w0c[16];
    #pragma unroll
    for (int j = 0; j < 16; ++j) w0c[j] = w0[j*256 + t];
    float2 y0[16];
    #pragma unroll
    for (int j = 0; j < 16; ++j) {
        float2 p = lds[swz(j*256 + t)];
        y0[j].x = w0c[j] * p.x;
        y0[j].y = w0c[j] * p.y;
    }
    #pragma unroll
    for (int i = 0; i < 16; ++i) {
        float a = xA[i*256 + t], b = xB[i*256 + t];    // residual re-read: L2/L3-hot
        #pragma unroll
        for (int j = 0; j < 16; ++j) {
            float s = l0[i*16 + j];
            a = fmaf(s, y0[j].x, a);
            b = fmaf(s, y0[j].y, b);
        }
        __builtin_nontemporal_store(a, &oA[i*256 + t]);   // 256B/wave/inst: full lines
        __builtin_nontemporal_store(b, &oB[i*256 + t]);
    }
}

__global__ __launch_bounds__(256, 4) void butterfly10_kernel(
    const float* __restrict__ x,
    const float* __restrict__ w0, const float* __restrict__ w1, const float* __restrict__ w2,
    const float* __restrict__ l0, const float* __restrict__ l1, const float* __restrict__ l2,
    float* __restrict__ out)
{
    __shared__ float2 lds[N];                          // 32 KiB
    const int t = threadIdx.x;
    const int b1 = t >> 4, c1 = t & 15;
    const size_t row0 = (size_t)blockIdx.x * 4;        // 4 adjacent rows = 2 pairs
    const float* __restrict__ xA = x + row0 * N;
    const float* __restrict__ xB = xA + N;
    const float* __restrict__ xC = xB + N;
    const float* __restrict__ xD = xC + N;
    float* __restrict__ oA = out + row0 * N;
    float* __restrict__ oB = oA + N;
    float* __restrict__ oC = oB + N;
    float* __restrict__ oD = oC + N;

    // issue ALL 16 dwordx4 loads up front: pair-1's stay in flight under pair-0 compute
    float vA[16], vB[16], vC[16], vD[16];
    {
        const float4* qA = (const float4*)(xA + t * 16);
        const float4* qB = (const float4*)(xB + t * 16);
        const float4* qC = (const float4*)(xC + t * 16);
        const float4* qD = (const float4*)(xD + t * 16);
        #pragma unroll
        for (int q = 0; q < 4; ++q) {
            float4 f = qA[q];
            vA[q*4+0]=f.x; vA[q*4+1]=f.y; vA[q*4+2]=f.z; vA[q*4+3]=f.w;
        }
        #pragma unroll
        for (int q = 0; q < 4; ++q) {
            float4 f = qB[q];
            vB[q*4+0]=f.x; vB[q*4+1]=f.y; vB[q*4+2]=f.z; vB[q*4+3]=f.w;
        }
        #pragma unroll
        for (int q = 0; q < 4; ++q) {
            float4 f = qC[q];
            vC[q*4+0]=f.x; vC[q*4+1]=f.y; vC[q*4+2]=f.z; vC[q*4+3]=f.w;
        }
        #pragma unroll
        for (int q = 0; q < 4; ++q) {
            float4 f = qD[q];
            vD[q*4+0]=f.x; vD[q*4+1]=f.y; vD[q*4+2]=f.z; vD[q*4+3]=f.w;
        }
    }

    do_pair<false, true >(lds, t, b1, c1, vA, vB, xA, xB, oA, oB,
                          w0, w1, w2, l0, l1, l2, vC, vD);
    do_pair<true,  false>(lds, t, b1, c1, vC, vD, xC, xD, oC, oD,
                          w0, w1, w2, l0, l1, l2, vC, vD);
}

extern "C" void kernel_launch(void* const* d_in, const int* in_sizes, int n_in,
                              void* d_out, int out_size, void* d_ws, size_t ws_size,
                              hipStream_t stream) {
    const float* x  = (const float*)d_in[0];
    const float* w0 = (const float*)d_in[1];
    const float* w1 = (const float*)d_in[2];
    const float* w2 = (const float*)d_in[3];
    const float* l0 = (const float*)d_in[4];
    const float* l1 = (const float*)d_in[5];
    const float* l2 = (const float*)d_in[6];
    float* out = (float*)d_out;
    const int rows = in_sizes[0] / N;
    butterfly10_kernel<<<rows / 4, 256, 0, stream>>>(x, w0, w1, w2, l0, l1, l2, out);
}